// Round 10
// baseline (285.041 us; speedup 1.0000x reference)
//
#include <hip/hip_runtime.h>
#include <hip/hip_bf16.h>

#define NF 128   // F_IN == F_OUT == 128

typedef __attribute__((ext_vector_type(8))) short short8;   // 8 bf16 = 4 VGPRs (MFMA A/B frag)
typedef __attribute__((ext_vector_type(4))) float f32x4;    // MFMA C/D frag

__device__ __forceinline__ ushort f2bf(float f) {
    union { __hip_bfloat16 h; ushort u; } c;
    c.h = __float2bfloat16(f);
    return c.u;
}
__device__ __forceinline__ float bf_lo(uint u) { return __uint_as_float(u << 16); }
__device__ __forceinline__ float bf_hi(uint u) { return __uint_as_float(u & 0xffff0000u); }

#define EPB 4096   // edges per block in hist/passC

// ---------------------------------------------------------------------------
// Kernel 1: convert x, W1, W2 to bf16; blocks < nblkC also histogram their
// EPB-edge slice into binCnt (bin = row>>9). stats/binCnt/binOff zeroed by
// hipMemsetAsync before this launch.
// ---------------------------------------------------------------------------
__global__ void cvt_hist_kernel(const float* __restrict__ x, const float* __restrict__ W1,
                                const float* __restrict__ W2, ushort* __restrict__ xb,
                                ushort* __restrict__ W1b, ushort* __restrict__ W2b,
                                const int* __restrict__ ei, int* __restrict__ binCnt,
                                int nx4, int nblkC, int E) {
    __shared__ int lcnt[256];
    int t = threadIdx.x;
    int blk = blockIdx.x;
    if (blk < nblkC) {
        lcnt[t] = 0;
        __syncthreads();
        int base = blk * EPB;
#pragma unroll
        for (int it = 0; it < EPB / 256; it++) {
            int e = base + it * 256 + t;
            if (e < E) atomicAdd(&lcnt[ei[e] >> 9], 1);
        }
        __syncthreads();
        int c = lcnt[t];
        if (c) atomicAdd(&binCnt[t], c);
    }
    int gid = blk * 256 + t;
    const float* src;
    ushort* dst;
    int idx;
    if (gid < nx4) { src = x; dst = xb; idx = gid; }
    else if (gid < nx4 + 4096) { src = W1; dst = W1b; idx = gid - nx4; }
    else if (gid < nx4 + 8192) { src = W2; dst = W2b; idx = gid - nx4 - 4096; }
    else return;
    float4 v = reinterpret_cast<const float4*>(src)[idx];
    ushort4 o;
    o.x = f2bf(v.x); o.y = f2bf(v.y); o.z = f2bf(v.z); o.w = f2bf(v.w);
    reinterpret_cast<ushort4*>(dst)[idx] = o;
}

// ---------------------------------------------------------------------------
// passC: block-local counting sort of EPB edges by bin in LDS, chunk
// reservation via binOff atomics, coalesced bin-grouped pair write.
// ---------------------------------------------------------------------------
__global__ void passC_kernel(const int* __restrict__ ei, const int* __restrict__ binCnt,
                             int* __restrict__ binOff, uint2* __restrict__ pair, int E) {
    __shared__ uint2 sorted[EPB];   // 32 KB
    __shared__ int lcnt[256];
    __shared__ int lofs[256];
    __shared__ int scanB[256];
    __shared__ int lcur[256];
    __shared__ int gdelta[256];
    int t = threadIdx.x;
    lcnt[t] = 0;
    lcur[t] = 0;
    __syncthreads();
    int base = blockIdx.x * EPB;
    int rows[EPB / 256], cols[EPB / 256];
#pragma unroll
    for (int it = 0; it < EPB / 256; it++) {
        int e = base + it * 256 + t;
        rows[it] = (e < E) ? ei[e] : -1;
        cols[it] = (e < E) ? ei[E + e] : 0;
        if (rows[it] >= 0) atomicAdd(&lcnt[rows[it] >> 9], 1);
    }
    __syncthreads();
    int v = lcnt[t];
    lofs[t] = v;
    int bc = binCnt[t];
    scanB[t] = bc;
    __syncthreads();
#pragma unroll
    for (int off = 1; off < 256; off <<= 1) {
        int u1 = (t >= off) ? lofs[t - off] : 0;
        int u2 = (t >= off) ? scanB[t - off] : 0;
        __syncthreads();
        lofs[t] += u1;
        scanB[t] += u2;
        __syncthreads();
    }
    int myOfs = lofs[t] - v;
    int binBase_t = scanB[t] - bc;
    int g = v ? atomicAdd(&binOff[t], v) : 0;
    __syncthreads();
    lofs[t] = myOfs;
    gdelta[t] = binBase_t + g - myOfs;
    __syncthreads();
#pragma unroll
    for (int it = 0; it < EPB / 256; it++) {
        if (rows[it] >= 0) {
            int b = rows[it] >> 9;
            int p = lofs[b] + atomicAdd(&lcur[b], 1);
            sorted[p] = make_uint2((uint)rows[it], (uint)cols[it]);
        }
    }
    __syncthreads();
    int nvalid = min(EPB, E - base);
    for (int i = t; i < nvalid; i += 256) {
        uint2 pr = sorted[i];
        pair[gdelta[pr.x >> 9] + i] = pr;
    }
}

// ---------------------------------------------------------------------------
// passDE: per-bin histogram + LDS scan -> rowptr, LDS-cursor fill -> adj.
// ---------------------------------------------------------------------------
__global__ void passDE_kernel(const uint2* __restrict__ pair, const int* __restrict__ binCnt,
                              int* __restrict__ rowptr, int* __restrict__ adj, int N, int E) {
    __shared__ int hist[512];
    __shared__ int s2[256];
    __shared__ int cur[512];
    int t = threadIdx.x;
    int b = blockIdx.x;
    hist[t] = 0;
    hist[t + 256] = 0;
    s2[t] = (t < b) ? binCnt[t] : 0;
    __syncthreads();
#pragma unroll
    for (int off = 128; off > 0; off >>= 1) {
        if (t < off) s2[t] += s2[t + off];
        __syncthreads();
    }
    int base = s2[0];
    int cnt = binCnt[b];
    __syncthreads();
    for (int i = t; i < cnt; i += 256)
        atomicAdd(&hist[pair[base + i].x & 511], 1);
    __syncthreads();
    int h0 = hist[2 * t], h1 = hist[2 * t + 1];
    s2[t] = h0 + h1;
    __syncthreads();
#pragma unroll
    for (int off = 1; off < 256; off <<= 1) {
        int u = (t >= off) ? s2[t - off] : 0;
        __syncthreads();
        s2[t] += u;
        __syncthreads();
    }
    int e0 = base + s2[t] - (h0 + h1);
    int e1 = e0 + h0;
    int g0 = b * 512 + 2 * t;
    if (g0 < N) rowptr[g0] = e0;
    if (g0 + 1 < N) rowptr[g0 + 1] = e1;
    if (t == 0 && b == gridDim.x - 1) rowptr[N] = E;
    cur[2 * t] = e0;
    cur[2 * t + 1] = e1;
    __syncthreads();
    for (int i = t; i < cnt; i += 256) {
        uint2 p = pair[base + i];
        int slot = atomicAdd(&cur[p.x & 511], 1);
        adj[slot] = (int)p.y;
    }
}

#define ACCV(v)                                                   \
    a0 += bf_lo((v).x); a1 += bf_hi((v).x);                       \
    a2 += bf_lo((v).y); a3 += bf_hi((v).y);                       \
    a4 += bf_lo((v).z); a5 += bf_hi((v).z);                       \
    a6 += bf_lo((v).w); a7 += bf_hi((v).w);

// ---------------------------------------------------------------------------
// mgemm0_fused: gather + GEMM1 + BN stats in one kernel.
// Block tile 128x128, K=128. Gather phase: each block aggregates its 128 rows
// (16 lanes/node, uint4/lane, unroll 8/4/2/1) directly into the As LDS tile
// as bf16 (no aggb round-trip). Then 4 waves (2x2), wave = 4x4 of 16x16x32
// MFMA; h written as bf16 to hb; fused BN sum/sumsq into stats.
// ---------------------------------------------------------------------------
__global__ __launch_bounds__(256) void mgemm0_fused(
    const uint4* __restrict__ xb4, const int* __restrict__ rowptr,
    const int* __restrict__ adj, const float* __restrict__ eps,
    const ushort* __restrict__ Wb, const float* __restrict__ bias,
    ushort* __restrict__ hb, float* __restrict__ stats, int N) {
    __shared__ ushort As[128 * 136];
    __shared__ ushort Bs[128 * 136];
    __shared__ float redS[256];
    __shared__ float redQ[256];

    const int t = threadIdx.x;
    const int row0 = blockIdx.x * 128;
    const int r16 = t >> 4;        // 0..15
    const int l16i = t & 15;       // lane within node / k-offset group

    // ---- stage W ----
#pragma unroll
    for (int it = 0; it < 8; it++) {
        int row = it * 16 + r16;
        uint4 w = *reinterpret_cast<const uint4*>(Wb + row * NF + l16i * 8);
        *reinterpret_cast<uint4*>(&Bs[row * 136 + l16i * 8]) = w;
    }

    // ---- gather phase: aggregate 128 rows into As ----
    float s = 1.0f + eps[0];
#pragma unroll 1
    for (int it = 0; it < 8; it++) {
        int row = it * 16 + r16;
        int node = row0 + row;
        float a0 = 0.f, a1 = 0.f, a2 = 0.f, a3 = 0.f;
        float a4 = 0.f, a5 = 0.f, a6 = 0.f, a7 = 0.f;
        if (node < N) {
            uint4 u = xb4[(size_t)node * 16 + l16i];
            a0 = bf_lo(u.x) * s; a1 = bf_hi(u.x) * s;
            a2 = bf_lo(u.y) * s; a3 = bf_hi(u.y) * s;
            a4 = bf_lo(u.z) * s; a5 = bf_hi(u.z) * s;
            a6 = bf_lo(u.w) * s; a7 = bf_hi(u.w) * s;
            int j = rowptr[node], end = rowptr[node + 1];
            for (; j + 8 <= end; j += 8) {
                int c0 = adj[j],     c1 = adj[j + 1], c2 = adj[j + 2], c3 = adj[j + 3];
                int c4 = adj[j + 4], c5 = adj[j + 5], c6 = adj[j + 6], c7 = adj[j + 7];
                uint4 v0 = xb4[(size_t)c0 * 16 + l16i];
                uint4 v1 = xb4[(size_t)c1 * 16 + l16i];
                uint4 v2 = xb4[(size_t)c2 * 16 + l16i];
                uint4 v3 = xb4[(size_t)c3 * 16 + l16i];
                uint4 v4 = xb4[(size_t)c4 * 16 + l16i];
                uint4 v5 = xb4[(size_t)c5 * 16 + l16i];
                uint4 v6 = xb4[(size_t)c6 * 16 + l16i];
                uint4 v7 = xb4[(size_t)c7 * 16 + l16i];
                ACCV(v0) ACCV(v1) ACCV(v2) ACCV(v3)
                ACCV(v4) ACCV(v5) ACCV(v6) ACCV(v7)
            }
            if (j + 4 <= end) {
                int c0 = adj[j], c1 = adj[j + 1], c2 = adj[j + 2], c3 = adj[j + 3];
                uint4 v0 = xb4[(size_t)c0 * 16 + l16i];
                uint4 v1 = xb4[(size_t)c1 * 16 + l16i];
                uint4 v2 = xb4[(size_t)c2 * 16 + l16i];
                uint4 v3 = xb4[(size_t)c3 * 16 + l16i];
                ACCV(v0) ACCV(v1) ACCV(v2) ACCV(v3)
                j += 4;
            }
            if (j + 2 <= end) {
                int c0 = adj[j], c1 = adj[j + 1];
                uint4 v0 = xb4[(size_t)c0 * 16 + l16i];
                uint4 v1 = xb4[(size_t)c1 * 16 + l16i];
                ACCV(v0) ACCV(v1)
                j += 2;
            }
            if (j < end) {
                uint4 v0 = xb4[(size_t)adj[j] * 16 + l16i];
                ACCV(v0)
            }
        }
        uint4 o;
        o.x = (uint)f2bf(a0) | ((uint)f2bf(a1) << 16);
        o.y = (uint)f2bf(a2) | ((uint)f2bf(a3) << 16);
        o.z = (uint)f2bf(a4) | ((uint)f2bf(a5) << 16);
        o.w = (uint)f2bf(a6) | ((uint)f2bf(a7) << 16);
        *reinterpret_cast<uint4*>(&As[row * 136 + l16i * 8]) = o;
    }
    __syncthreads();

    // ---- MFMA ----
    const int wid = t >> 6;
    const int lane = t & 63;
    const int quad = lane >> 4;
    const int l16 = lane & 15;
    const int wm = wid >> 1;
    const int wn = wid & 1;

    f32x4 acc[4][4];
#pragma unroll
    for (int tm = 0; tm < 4; tm++)
#pragma unroll
        for (int tn = 0; tn < 4; tn++) acc[tm][tn] = (f32x4)(0.0f);

#pragma unroll
    for (int ks = 0; ks < 4; ks++) {
        short8 a[4], b[4];
#pragma unroll
        for (int tm = 0; tm < 4; tm++)
            a[tm] = *reinterpret_cast<const short8*>(
                &As[(wm * 64 + tm * 16 + l16) * 136 + ks * 32 + quad * 8]);
#pragma unroll
        for (int tn = 0; tn < 4; tn++)
            b[tn] = *reinterpret_cast<const short8*>(
                &Bs[(wn * 64 + tn * 16 + l16) * 136 + ks * 32 + quad * 8]);
#pragma unroll
        for (int tm = 0; tm < 4; tm++)
#pragma unroll
            for (int tn = 0; tn < 4; tn++)
                acc[tm][tn] = __builtin_amdgcn_mfma_f32_16x16x32_bf16(a[tm], b[tn],
                                                                      acc[tm][tn], 0, 0, 0);
    }

    // ---- epilogue: bias, bf16 h -> hb, fused BN stats ----
    float bs[4];
#pragma unroll
    for (int tn = 0; tn < 4; tn++) bs[tn] = bias[wn * 64 + tn * 16 + l16];

    float ssum[4] = {0.f, 0.f, 0.f, 0.f}, sq[4] = {0.f, 0.f, 0.f, 0.f};
#pragma unroll
    for (int tm = 0; tm < 4; tm++) {
        int rb = wm * 64 + tm * 16 + quad * 4;
#pragma unroll
        for (int reg = 0; reg < 4; reg++) {
            int gr = row0 + rb + reg;
            bool ok = gr < N;
#pragma unroll
            for (int tn = 0; tn < 4; tn++) {
                int col = wn * 64 + tn * 16 + l16;
                float h = acc[tm][tn][reg] + bs[tn];
                if (ok) {
                    hb[(size_t)gr * NF + col] = f2bf(h);
                    ssum[tn] += h;
                    sq[tn] += h * h;
                }
            }
        }
    }

#pragma unroll
    for (int tn = 0; tn < 4; tn++) {
        float sv = ssum[tn], q = sq[tn];
        sv += __shfl_xor(sv, 16); sv += __shfl_xor(sv, 32);
        q += __shfl_xor(q, 16); q += __shfl_xor(q, 32);
        if (quad == 0) {
            int c = wn * 64 + tn * 16 + l16;
            redS[wm * 128 + c] = sv;
            redQ[wm * 128 + c] = q;
        }
    }
    __syncthreads();
    if (t < 128) {
        unsafeAtomicAdd(&stats[t], redS[t] + redS[128 + t]);
        unsafeAtomicAdd(&stats[128 + t], redQ[t] + redQ[128 + t]);
    }
}

// ---------------------------------------------------------------------------
// mgemm1: BN finalize in-prologue; A = relu(hb*scale+shift); fp32 out.
// ---------------------------------------------------------------------------
__global__ __launch_bounds__(256) void mgemm1_kernel(
    const ushort* __restrict__ hb, const ushort* __restrict__ Wb,
    const float* __restrict__ bias, float* __restrict__ out,
    const float* __restrict__ stats, const float* __restrict__ gamma,
    const float* __restrict__ beta, int N) {
    __shared__ ushort As[128 * 136];
    __shared__ ushort Bs[128 * 136];
    __shared__ float scL[128];
    __shared__ float shL[128];

    const int t = threadIdx.x;
    const int row0 = blockIdx.x * 128;
    const int r16 = t >> 4;
    const int c8 = (t & 15) * 8;

    if (t < 128) {
        float inv_n = 1.0f / (float)N;
        float mean = stats[t] * inv_n;
        float var = fmaxf(stats[128 + t] * inv_n - mean * mean, 0.0f);
        float s = gamma[t] * rsqrtf(var + 1e-5f);
        scL[t] = s;
        shL[t] = beta[t] - mean * s;
    }
    __syncthreads();

    float sc[8], sh[8];
#pragma unroll
    for (int i = 0; i < 8; i++) { sc[i] = scL[c8 + i]; sh[i] = shL[c8 + i]; }

#pragma unroll
    for (int it = 0; it < 8; it++) {
        int row = it * 16 + r16;
        int gr = row0 + row;
        uint4 v = make_uint4(0, 0, 0, 0);
        if (gr < N) v = *reinterpret_cast<const uint4*>(hb + (size_t)gr * NF + c8);
        float vv[8] = {bf_lo(v.x), bf_hi(v.x), bf_lo(v.y), bf_hi(v.y),
                       bf_lo(v.z), bf_hi(v.z), bf_lo(v.w), bf_hi(v.w)};
#pragma unroll
        for (int i = 0; i < 8; i++) vv[i] = fmaxf(vv[i] * sc[i] + sh[i], 0.0f);
        uint4 p;
        p.x = (uint)f2bf(vv[0]) | ((uint)f2bf(vv[1]) << 16);
        p.y = (uint)f2bf(vv[2]) | ((uint)f2bf(vv[3]) << 16);
        p.z = (uint)f2bf(vv[4]) | ((uint)f2bf(vv[5]) << 16);
        p.w = (uint)f2bf(vv[6]) | ((uint)f2bf(vv[7]) << 16);
        *reinterpret_cast<uint4*>(&As[row * 136 + c8]) = p;
        uint4 w = *reinterpret_cast<const uint4*>(Wb + row * NF + c8);
        *reinterpret_cast<uint4*>(&Bs[row * 136 + c8]) = w;
    }
    __syncthreads();

    const int wid = t >> 6;
    const int lane = t & 63;
    const int quad = lane >> 4;
    const int l16 = lane & 15;
    const int wm = wid >> 1;
    const int wn = wid & 1;

    f32x4 acc[4][4];
#pragma unroll
    for (int tm = 0; tm < 4; tm++)
#pragma unroll
        for (int tn = 0; tn < 4; tn++) acc[tm][tn] = (f32x4)(0.0f);

#pragma unroll
    for (int ks = 0; ks < 4; ks++) {
        short8 a[4], b[4];
#pragma unroll
        for (int tm = 0; tm < 4; tm++)
            a[tm] = *reinterpret_cast<const short8*>(
                &As[(wm * 64 + tm * 16 + l16) * 136 + ks * 32 + quad * 8]);
#pragma unroll
        for (int tn = 0; tn < 4; tn++)
            b[tn] = *reinterpret_cast<const short8*>(
                &Bs[(wn * 64 + tn * 16 + l16) * 136 + ks * 32 + quad * 8]);
#pragma unroll
        for (int tm = 0; tm < 4; tm++)
#pragma unroll
            for (int tn = 0; tn < 4; tn++)
                acc[tm][tn] = __builtin_amdgcn_mfma_f32_16x16x32_bf16(a[tm], b[tn],
                                                                      acc[tm][tn], 0, 0, 0);
    }

    float bs[4];
#pragma unroll
    for (int tn = 0; tn < 4; tn++) bs[tn] = bias[wn * 64 + tn * 16 + l16];

#pragma unroll
    for (int tm = 0; tm < 4; tm++) {
        int rb = wm * 64 + tm * 16 + quad * 4;
#pragma unroll
        for (int reg = 0; reg < 4; reg++) {
            int gr = row0 + rb + reg;
            if (gr < N) {
#pragma unroll
                for (int tn = 0; tn < 4; tn++) {
                    int col = wn * 64 + tn * 16 + l16;
                    out[(size_t)gr * NF + col] = acc[tm][tn][reg] + bs[tn];
                }
            }
        }
    }
}

extern "C" void kernel_launch(void* const* d_in, const int* in_sizes, int n_in,
                              void* d_out, int out_size, void* d_ws, size_t ws_size,
                              hipStream_t stream) {
    const float* x     = (const float*)d_in[0];
    const int* ei      = (const int*)d_in[1];  // [2, E], int32 per harness
    const float* eps   = (const float*)d_in[2];
    const float* W1    = (const float*)d_in[3];
    const float* b1    = (const float*)d_in[4];
    const float* gamma = (const float*)d_in[5];
    const float* beta  = (const float*)d_in[6];
    const float* W2    = (const float*)d_in[7];
    const float* b2    = (const float*)d_in[8];
    float* out         = (float*)d_out;

    const int N = in_sizes[0] / NF;   // 100000
    const int E = in_sizes[1] / 2;    // 1600000

    const int NB = (N + 511) >> 9;            // bins (196)
    const int nblkC = (E + EPB - 1) / EPB;    // hist/passC blocks (391)

    // workspace layout (~58 MB). pair aliases hb (pair dead before mgemm0).
    ushort* xb     = (ushort*)d_ws;                 // N*128 bf16
    ushort* hb     = xb + (size_t)N * NF;           // N*128 bf16
    ushort* W1b    = hb + (size_t)N * NF;           // 16384 bf16
    ushort* W2b    = W1b + NF * NF;                 // 16384 bf16
    float*  stats  = (float*)(W2b + NF * NF);       // 512 f32
    int*    binCnt = (int*)(stats + 512);           // 256
    int*    binOff = binCnt + 256;                  // 256
    int*    rowptr = binOff + 256;                  // N+1
    int*    adj    = rowptr + (N + 1);              // E
    uint2*  pair   = (uint2*)hb;                    // E pairs

    // zero stats(512f) + binCnt(256) + binOff(256) = 4 KB contiguous
    hipMemsetAsync(stats, 0, 4096, stream);

    int nx4 = N * 32;
    int cvtBlocks = (nx4 + 8192 + 255) / 256;
    cvt_hist_kernel<<<cvtBlocks, 256, 0, stream>>>(x, W1, W2, xb, W1b, W2b, ei, binCnt,
                                                   nx4, nblkC, E);
    passC_kernel<<<nblkC, 256, 0, stream>>>(ei, binCnt, binOff, pair, E);
    passDE_kernel<<<NB, 256, 0, stream>>>(pair, binCnt, rowptr, adj, N, E);

    int gblocks = (N + 127) / 128;
    mgemm0_fused<<<gblocks, 256, 0, stream>>>((const uint4*)xb, rowptr, adj, eps,
                                              W1b, b1, hb, stats, N);
    mgemm1_kernel<<<gblocks, 256, 0, stream>>>(hb, W2b, b2, out, stats, gamma, beta, N);
}